// Round 1
// baseline (485.892 us; speedup 1.0000x reference)
//
#include <hip/hip_runtime.h>

typedef short short8 __attribute__((ext_vector_type(8)));
typedef short short4v __attribute__((ext_vector_type(4)));
typedef float f32x4 __attribute__((ext_vector_type(4)));

typedef __attribute__((address_space(1))) void gvoid;
typedef __attribute__((address_space(3))) void lvoid;

#define DEV static __device__ __forceinline__

constexpr int Dm = 512;   // model dim
constexpr int Sm = 4096;  // seq len
constexpr int Hh = 8;     // heads

DEV short f2bf(float f) {
  union { float f; unsigned u; } v; v.f = f;
  unsigned r = v.u + 0x7FFFu + ((v.u >> 16) & 1u);
  return (short)(r >> 16);
}

DEV void async16(const void* g, void* l) {
  __builtin_amdgcn_global_load_lds((gvoid*)g, (lvoid*)l, 16, 0, 0);
}

// ---------------- input casts ----------------
__global__ __launch_bounds__(256) void cast_qkv(
    const float* __restrict__ q, const float* __restrict__ k,
    const float* __restrict__ v, short* __restrict__ xq,
    short* __restrict__ xk, short* __restrict__ xv) {
  int t = blockIdx.y;
  const float* src = (t == 0) ? q : (t == 1) ? k : v;
  short* dst = (t == 0) ? xq : (t == 1) ? xk : xv;
  long i = (long)(blockIdx.x * 256 + threadIdx.x) * 4;
  float4 f = *(const float4*)(src + i);
  short4v o;
  o[0] = f2bf(f.x); o[1] = f2bf(f.y); o[2] = f2bf(f.z); o[3] = f2bf(f.w);
  *(short4v*)(dst + i) = o;
}

// Wt[w][n][k] = W_w[k][n]  (bf16), w in {q,k,v,o}
__global__ __launch_bounds__(256) void wtrans(
    const float* __restrict__ wq, const float* __restrict__ wk,
    const float* __restrict__ wv, const float* __restrict__ wo,
    short* __restrict__ wt) {
  int idx = blockIdx.x * 256 + threadIdx.x;      // 0 .. 4*512*512-1
  int w = idx >> 18, rem = idx & 262143;
  int n = rem >> 9, kk = rem & 511;
  const float* W = (w == 0) ? wq : (w == 1) ? wk : (w == 2) ? wv : wo;
  wt[idx] = f2bf(W[kk * 512 + n]);
}

// ---------------- GEMM: Y[m][n] = sum_k A[m][k]*Bt[n][k] + bias[n] ----------
// A: bf16 [M,512], Bt: bf16 [512,512], Y: bf16 or f32 [M,512]
template <bool OUT_BF16>
__global__ __launch_bounds__(256) void gemm_bt(
    const short* __restrict__ A, const short* __restrict__ Bt,
    const float* __restrict__ bias, void* __restrict__ Yv) {
  constexpr int K = 512, N = 512, BK = 64;
  __shared__ short As[128 * BK];
  __shared__ short Bs[128 * BK];
  const int tid = threadIdx.x, lane = tid & 63, w = tid >> 6;
  const int lm = lane & 15, lg = lane >> 4;
  const int wr = w >> 1, wc = w & 1;
  const long bm = (long)blockIdx.y * 128;
  const long bn = (long)blockIdx.x * 128;
  f32x4 zero = {0.f, 0.f, 0.f, 0.f};
  f32x4 acc[4][4];
  for (int m = 0; m < 4; ++m)
    for (int n = 0; n < 4; ++n) acc[m][n] = zero;
  for (int k0 = 0; k0 < K; k0 += BK) {
    __syncthreads();
    for (int t = 0; t < 4; ++t) {
      int flat = t * 256 + tid;        // 0..1023 ; row = flat/8, 8x16B per row
      int row = flat >> 3, c8 = flat & 7;
      async16(A + (bm + row) * K + k0 + c8 * 8, As + flat * 8);
    }
    for (int t = 0; t < 4; ++t) {
      int flat = t * 256 + tid;
      int row = flat >> 3, c8 = flat & 7;
      async16(Bt + (bn + row) * K + k0 + c8 * 8, Bs + flat * 8);
    }
    __syncthreads();
    for (int kk = 0; kk < 2; ++kk) {
      short8 a[4], b[4];
      for (int m = 0; m < 4; ++m)
        a[m] = *(const short8*)(As + (wr * 64 + m * 16 + lm) * BK + kk * 32 + lg * 8);
      for (int n = 0; n < 4; ++n)
        b[n] = *(const short8*)(Bs + (wc * 64 + n * 16 + lm) * BK + kk * 32 + lg * 8);
      for (int m = 0; m < 4; ++m)
        for (int n = 0; n < 4; ++n)
          acc[m][n] = __builtin_amdgcn_mfma_f32_16x16x32_bf16(a[m], b[n], acc[m][n], 0, 0, 0);
    }
  }
  for (int m = 0; m < 4; ++m)
    for (int n = 0; n < 4; ++n) {
      long row0 = bm + wr * 64 + m * 16 + lg * 4;
      int col = (int)bn + wc * 64 + n * 16 + lm;
      float bb = bias[col];
      for (int j = 0; j < 4; ++j) {
        float val = acc[m][n][j] + bb;
        if (OUT_BF16)
          ((short*)Yv)[(row0 + j) * N + col] = f2bf(val);
        else
          ((float*)Yv)[(row0 + j) * N + col] = val;
      }
    }
}

// ---------------- flash attention ----------------
// Q,K,V,O: bf16 [B*S, 512] with head h at cols [h*64, h*64+64)
__global__ __launch_bounds__(256) void attn(
    const short* __restrict__ Qb, const short* __restrict__ Kb,
    const short* __restrict__ Vb, short* __restrict__ Ob) {
  __shared__ short Ks[64 * 64];  // [kv][d]
  __shared__ short Vt[64 * 64];  // [d][kv]
  __shared__ short Ps[64 * 64];  // [q][kv]
  const int tid = threadIdx.x, lane = tid & 63, w = tid >> 6;
  const int lm = lane & 15, lg = lane >> 4;
  const int bh = blockIdx.y, b = bh >> 3, h = bh & 7;
  const long base = (long)b * Sm * Dm + h * 64;
  const int q0 = blockIdx.x * 64 + w * 16;
  short8 qf[2];
  for (int c = 0; c < 2; ++c)
    qf[c] = *(const short8*)(Qb + base + (long)(q0 + lm) * Dm + c * 32 + lg * 8);
  f32x4 zero = {0.f, 0.f, 0.f, 0.f};
  f32x4 o[4];
  for (int dt = 0; dt < 4; ++dt) o[dt] = zero;
  float mrun[4], lrun[4];
  for (int j = 0; j < 4; ++j) { mrun[j] = -1e30f; lrun[j] = 0.f; }

  for (int kv0 = 0; kv0 < Sm; kv0 += 64) {
    __syncthreads();  // all waves done reading prev K/V tiles
    // stage K tile [64][64] via async global->LDS (2 x 4KB)
    for (int t = 0; t < 2; ++t) {
      int flat = t * 256 + tid;          // 0..511 ; row = flat/8
      int row = flat >> 3, c8 = flat & 7;
      async16(Kb + base + (long)(kv0 + row) * Dm + c8 * 8, Ks + flat * 8);
    }
    // stage V transposed via registers
    for (int t = 0; t < 2; ++t) {
      int flat = t * 256 + tid;
      int row = flat >> 3, c8 = flat & 7;
      short8 vv = *(const short8*)(Vb + base + (long)(kv0 + row) * Dm + c8 * 8);
      for (int j = 0; j < 8; ++j) Vt[(c8 * 8 + j) * 64 + row] = vv[j];
    }
    __syncthreads();  // staging complete (vmcnt+lgkm drained by barrier)

    // QK^T: score[q=lg*4+j][kv=n*16+lm]
    f32x4 sc[4];
    for (int n = 0; n < 4; ++n) {
      short8 kf0 = *(const short8*)(Ks + (n * 16 + lm) * 64 + lg * 8);
      short8 kf1 = *(const short8*)(Ks + (n * 16 + lm) * 64 + 32 + lg * 8);
      f32x4 z = zero;
      z = __builtin_amdgcn_mfma_f32_16x16x32_bf16(qf[0], kf0, z, 0, 0, 0);
      z = __builtin_amdgcn_mfma_f32_16x16x32_bf16(qf[1], kf1, z, 0, 0, 0);
      for (int j = 0; j < 4; ++j) sc[n][j] = z[j] * 0.125f;  // / sqrt(64)
    }
    // online softmax: row reductions over kv (4 tiles in-reg + 16-lane shfl)
    float mnew[4];
    for (int j = 0; j < 4; ++j)
      mnew[j] = fmaxf(fmaxf(sc[0][j], sc[1][j]), fmaxf(sc[2][j], sc[3][j]));
    for (int mask = 1; mask < 16; mask <<= 1)
      for (int j = 0; j < 4; ++j)
        mnew[j] = fmaxf(mnew[j], __shfl_xor(mnew[j], mask, 64));
    float mi[4], cc[4], lnew[4];
    for (int j = 0; j < 4; ++j) {
      mi[j] = fmaxf(mrun[j], mnew[j]);
      cc[j] = __expf(mrun[j] - mi[j]);
      mrun[j] = mi[j];
      lnew[j] = 0.f;
    }
    for (int n = 0; n < 4; ++n)
      for (int j = 0; j < 4; ++j) {
        float p = __expf(sc[n][j] - mi[j]);
        lnew[j] += p;
        Ps[(w * 16 + lg * 4 + j) * 64 + n * 16 + lm] = f2bf(p);
      }
    for (int mask = 1; mask < 16; mask <<= 1)
      for (int j = 0; j < 4; ++j)
        lnew[j] += __shfl_xor(lnew[j], mask, 64);
    for (int j = 0; j < 4; ++j) lrun[j] = lrun[j] * cc[j] + lnew[j];
    for (int dt = 0; dt < 4; ++dt)
      for (int j = 0; j < 4; ++j) o[dt][j] *= cc[j];
    __syncthreads();  // P writes visible for frag reads

    // PV: O[q][d] += sum_kv P[q][kv] * V[kv][d]
    short8 pf[2];
    for (int kc = 0; kc < 2; ++kc)
      pf[kc] = *(const short8*)(Ps + (w * 16 + lm) * 64 + kc * 32 + lg * 8);
    for (int dt = 0; dt < 4; ++dt)
      for (int kc = 0; kc < 2; ++kc) {
        short8 vf = *(const short8*)(Vt + (dt * 16 + lm) * 64 + kc * 32 + lg * 8);
        o[dt] = __builtin_amdgcn_mfma_f32_16x16x32_bf16(pf[kc], vf, o[dt], 0, 0, 0);
      }
  }
  // epilogue: normalize and store bf16
  for (int dt = 0; dt < 4; ++dt)
    for (int j = 0; j < 4; ++j) {
      float val = o[dt][j] / lrun[j];
      Ob[base + (long)(q0 + lg * 4 + j) * Dm + dt * 16 + lm] = f2bf(val);
    }
}

extern "C" void kernel_launch(void* const* d_in, const int* in_sizes, int n_in,
                              void* d_out, int out_size, void* d_ws, size_t ws_size,
                              hipStream_t stream) {
  const float* query = (const float*)d_in[0];
  const float* key_  = (const float*)d_in[1];
  const float* value = (const float*)d_in[2];
  const float* Wq = (const float*)d_in[3]; const float* bq = (const float*)d_in[4];
  const float* Wk = (const float*)d_in[5]; const float* bk = (const float*)d_in[6];
  const float* Wv = (const float*)d_in[7]; const float* bv = (const float*)d_in[8];
  const float* Wo = (const float*)d_in[9]; const float* bo = (const float*)d_in[10];

  const long NT = (long)2 * Sm * Dm;  // 4,194,304 elements per [B,S,D] tensor
  short* Xq = (short*)d_ws;
  short* Xk = Xq + NT;
  short* Xv = Xk + NT;
  short* Wt = Xv + NT;                 // [4][512][512] bf16
  short* Qb = Wt + 4 * 512 * 512;
  short* Kb = Qb + NT;
  short* Vb = Kb + NT;
  short* Ob = Xq;                      // reuse Xq (dead after Q projection)

  cast_qkv<<<dim3(4096, 3), 256, 0, stream>>>(query, key_, value, Xq, Xk, Xv);
  wtrans<<<dim3(4096), 256, 0, stream>>>(Wq, Wk, Wv, Wo, Wt);

  gemm_bt<true><<<dim3(4, 64), 256, 0, stream>>>(Xq, Wt,             bq, Qb);
  gemm_bt<true><<<dim3(4, 64), 256, 0, stream>>>(Xk, Wt + 512 * 512, bk, Kb);
  gemm_bt<true><<<dim3(4, 64), 256, 0, stream>>>(Xv, Wt + 2 * 512 * 512, bv, Vb);

  attn<<<dim3(Sm / 64, 2 * Hh), 256, 0, stream>>>(Qb, Kb, Vb, Ob);

  gemm_bt<false><<<dim3(4, 64), 256, 0, stream>>>(Ob, Wt + 3 * 512 * 512, bo, d_out);
}

// Round 2
// 211.987 us; speedup vs baseline: 2.2921x; 2.2921x over previous
//
#include <hip/hip_runtime.h>

typedef short short8 __attribute__((ext_vector_type(8)));
typedef short short4v __attribute__((ext_vector_type(4)));
typedef float f32x4 __attribute__((ext_vector_type(4)));

typedef __attribute__((address_space(1))) void gvoid;
typedef __attribute__((address_space(3))) void lvoid;

#define DEV static __device__ __forceinline__

constexpr int Dm = 512;   // model dim
constexpr int Sm = 4096;  // seq len
constexpr int Hh = 8;     // heads

// 0.125 (=1/sqrt(64)) * log2(e): folded into Q projection so softmax runs in exp2 domain
#define QSCALE 0.18033688011112042f

DEV short f2bf(float f) {
  union { float f; unsigned u; } v; v.f = f;
  unsigned r = v.u + 0x7FFFu + ((v.u >> 16) & 1u);
  return (short)(r >> 16);
}

DEV float exp2_fast(float x) {
#if __has_builtin(__builtin_amdgcn_exp2f)
  return __builtin_amdgcn_exp2f(x);
#else
  return exp2f(x);
#endif
}

DEV unsigned cvt_pk_bf16(float lo, float hi) {
  unsigned r;
  asm("v_cvt_pk_bf16_f32 %0, %1, %2" : "=v"(r) : "v"(lo), "v"(hi));
  return r;
}

DEV void async16(const void* g, void* l) {
  __builtin_amdgcn_global_load_lds((gvoid*)g, (lvoid*)l, 16, 0, 0);
}

// ---------------- input casts ----------------
__global__ __launch_bounds__(256) void cast_qkv(
    const float* __restrict__ q, const float* __restrict__ k,
    const float* __restrict__ v, short* __restrict__ xq,
    short* __restrict__ xk, short* __restrict__ xv) {
  int t = blockIdx.y;
  const float* src = (t == 0) ? q : (t == 1) ? k : v;
  short* dst = (t == 0) ? xq : (t == 1) ? xk : xv;
  long i = (long)(blockIdx.x * 256 + threadIdx.x) * 4;
  float4 f = *(const float4*)(src + i);
  short4v o;
  o[0] = f2bf(f.x); o[1] = f2bf(f.y); o[2] = f2bf(f.z); o[3] = f2bf(f.w);
  *(short4v*)(dst + i) = o;
}

// Wt[w][n][k] = W_w[k][n]  (bf16), w in {q,k,v,o}
__global__ __launch_bounds__(256) void wtrans(
    const float* __restrict__ wq, const float* __restrict__ wk,
    const float* __restrict__ wv, const float* __restrict__ wo,
    short* __restrict__ wt) {
  int idx = blockIdx.x * 256 + threadIdx.x;      // 0 .. 4*512*512-1
  int w = idx >> 18, rem = idx & 262143;
  int n = rem >> 9, kk = rem & 511;
  const float* W = (w == 0) ? wq : (w == 1) ? wk : (w == 2) ? wv : wo;
  wt[idx] = f2bf(W[kk * 512 + n]);
}

// ---------------- V transpose: V[b*S+s][d] -> VT[b][d][s] ----------------
__global__ __launch_bounds__(256) void vtrans(
    const short* __restrict__ V, short* __restrict__ VT) {
  __shared__ short T[64 * 72];  // stride 72 shorts = 144B (16B-aligned rows)
  const int tid = threadIdx.x;
  const int s0 = blockIdx.x * 64, d0 = blockIdx.y * 64, b = blockIdx.z;
  for (int t = 0; t < 2; ++t) {
    int flat = t * 256 + tid;
    int sl = flat >> 3, c = flat & 7;
    short8 v = *(const short8*)(V + ((long)b * Sm + s0 + sl) * Dm + d0 + c * 8);
    for (int j = 0; j < 8; ++j) T[(c * 8 + j) * 72 + sl] = v[j];
  }
  __syncthreads();
  for (int t = 0; t < 2; ++t) {
    int flat = t * 256 + tid;
    int dl = flat >> 3, c = flat & 7;
    short8 v = *(const short8*)(T + dl * 72 + c * 8);
    *(short8*)(VT + ((long)b * Dm + d0 + dl) * Sm + s0 + c * 8) = v;
  }
}

// ---------------- GEMM: Y[m][n] = (sum_k A[m][k]*Bt[n][k] + bias[n])*scale ----
// A: bf16 [M,512], Bt: bf16 [512,512], Y: bf16 or f32 [M,512]
template <bool OUT_BF16>
__global__ __launch_bounds__(256) void gemm_bt(
    const short* __restrict__ A, const short* __restrict__ Bt,
    const float* __restrict__ bias, float scale, void* __restrict__ Yv) {
  constexpr int K = 512, N = 512, BK = 64;
  __shared__ short As[128 * BK];
  __shared__ short Bs[128 * BK];
  const int tid = threadIdx.x, lane = tid & 63, w = tid >> 6;
  const int lm = lane & 15, lg = lane >> 4;
  const int wr = w >> 1, wc = w & 1;
  const long bm = (long)blockIdx.y * 128;
  const long bn = (long)blockIdx.x * 128;
  f32x4 zero = {0.f, 0.f, 0.f, 0.f};
  f32x4 acc[4][4];
  for (int m = 0; m < 4; ++m)
    for (int n = 0; n < 4; ++n) acc[m][n] = zero;
  for (int k0 = 0; k0 < K; k0 += BK) {
    __syncthreads();
    // swizzled-source staging: LDS chunk (row,c) holds global chunk c^(row&7)
    for (int t = 0; t < 4; ++t) {
      int flat = t * 256 + tid;
      int row = flat >> 3, c = flat & 7;
      async16(A + (bm + row) * K + k0 + ((c ^ (row & 7)) * 8), As + flat * 8);
    }
    for (int t = 0; t < 4; ++t) {
      int flat = t * 256 + tid;
      int row = flat >> 3, c = flat & 7;
      async16(Bt + (bn + row) * K + k0 + ((c ^ (row & 7)) * 8), Bs + flat * 8);
    }
    __syncthreads();
    for (int kk = 0; kk < 2; ++kk) {
      short8 a[4], b[4];
      for (int m = 0; m < 4; ++m)
        a[m] = *(const short8*)(As + (wr * 64 + m * 16 + lm) * BK +
                                ((kk * 4 + lg) ^ (lm & 7)) * 8);
      for (int n = 0; n < 4; ++n)
        b[n] = *(const short8*)(Bs + (wc * 64 + n * 16 + lm) * BK +
                                ((kk * 4 + lg) ^ (lm & 7)) * 8);
      for (int m = 0; m < 4; ++m)
        for (int n = 0; n < 4; ++n)
          acc[m][n] = __builtin_amdgcn_mfma_f32_16x16x32_bf16(a[m], b[n], acc[m][n], 0, 0, 0);
    }
  }
  for (int m = 0; m < 4; ++m)
    for (int n = 0; n < 4; ++n) {
      long row0 = bm + wr * 64 + m * 16 + lg * 4;
      int col = (int)bn + wc * 64 + n * 16 + lm;
      float bb = bias[col];
      for (int j = 0; j < 4; ++j) {
        float val = (acc[m][n][j] + bb) * scale;
        if (OUT_BF16)
          ((short*)Yv)[(row0 + j) * N + col] = f2bf(val);
        else
          ((float*)Yv)[(row0 + j) * N + col] = val;
      }
    }
}

// ---------------- flash attention (swapped QK^T, swizzled LDS, 2-phase) -----
// Qb,Kb: bf16 [B*S, 512] (head h at cols h*64..); VTb: bf16 [B][512][S]
// Ob: bf16 [B*S, 512]
__global__ __launch_bounds__(256, 4) void attn(
    const short* __restrict__ Qb, const short* __restrict__ Kb,
    const short* __restrict__ VTb, short* __restrict__ Ob) {
  __shared__ short Ks[2][64 * 64];  // [kv][d], 16B-chunk c stored at c^(kv&7)
  __shared__ short Vt[2][64 * 64];  // [d][kv], chunk c stored at c^(d&7)
  __shared__ short Ps[4][16 * 64];  // per-wave [q][kv], swizzled
  const int tid = threadIdx.x, lane = tid & 63, w = tid >> 6;
  const int lm = lane & 15, lg = lane >> 4;
  const int bh = blockIdx.y, b = bh >> 3, h = bh & 7;
  const long baseQ = (long)b * Sm * Dm + h * 64;
  const long baseVT = ((long)b * Dm + h * 64) * Sm;
  const int q0w = blockIdx.x * 64 + w * 16;

  // Q fragment (B-operand for swapped QK^T): lane lm = q, regs = d
  short8 qf[2];
  for (int c = 0; c < 2; ++c)
    qf[c] = *(const short8*)(Qb + baseQ + (long)(q0w + lm) * Dm + c * 32 + lg * 8);

  f32x4 o[4];
  for (int dt = 0; dt < 4; ++dt) o[dt] = {0.f, 0.f, 0.f, 0.f};
  float mrun = -1e30f, lrun = 0.f;

  auto stage = [&](int buf, int kv0) {
    for (int t = 0; t < 2; ++t) {
      int flat = t * 256 + tid;
      int row = flat >> 3, c = flat & 7;  // row = kv-local
      async16(Kb + baseQ + (long)(kv0 + row) * Dm + ((c ^ (row & 7)) * 8),
              &Ks[buf][flat * 8]);
    }
    for (int t = 0; t < 2; ++t) {
      int flat = t * 256 + tid;
      int row = flat >> 3, c = flat & 7;  // row = d-local, c = kv chunk
      async16(VTb + baseVT + (long)row * Sm + kv0 + ((c ^ (row & 7)) * 8),
              &Vt[buf][flat * 8]);
    }
  };

  stage(0, 0);
  __syncthreads();  // drains vmcnt(0): tile 0 resident

  constexpr int NT = Sm / 64;
  for (int it = 0; it < NT; ++it) {
    const int cur = it & 1;
    if (it + 1 < NT) stage(cur ^ 1, (it + 1) * 64);  // prefetch, in flight over compute

    // QK^T swapped: D[kv][q]; lane: q = q0w+lm, kv = n*16 + lg*4 + j
    f32x4 sc[4];
    for (int n = 0; n < 4; ++n) {
      f32x4 z = {0.f, 0.f, 0.f, 0.f};
      for (int kk = 0; kk < 2; ++kk) {
        short8 kf = *(const short8*)(&Ks[cur][(n * 16 + lm) * 64 +
                                              ((kk * 4 + lg) ^ (lm & 7)) * 8]);
        z = __builtin_amdgcn_mfma_f32_16x16x32_bf16(kf, qf[kk], z, 0, 0, 0);
      }
      sc[n] = z;
    }
    // online softmax in exp2 domain (scale pre-folded into Q)
    float tmax = sc[0][0];
    for (int n = 0; n < 4; ++n)
      for (int j = 0; j < 4; ++j) tmax = fmaxf(tmax, sc[n][j]);
    tmax = fmaxf(tmax, __shfl_xor(tmax, 16, 64));
    tmax = fmaxf(tmax, __shfl_xor(tmax, 32, 64));
    float mi = fmaxf(mrun, tmax);
    float cc = exp2_fast(mrun - mi);
    mrun = mi;
    float lnew = 0.f;
    for (int n = 0; n < 4; ++n)
      for (int j = 0; j < 4; ++j) {
        float p = exp2_fast(sc[n][j] - mi);
        sc[n][j] = p;
        lnew += p;
      }
    lnew += __shfl_xor(lnew, 16, 64);
    lnew += __shfl_xor(lnew, 32, 64);
    lrun = lrun * cc + lnew;

    // pack P -> per-wave LDS (swizzled): row q=lm, logical col kv=n*16+lg*4
    for (int n = 0; n < 4; ++n) {
      uint2 val;
      val.x = cvt_pk_bf16(sc[n][0], sc[n][1]);
      val.y = cvt_pk_bf16(sc[n][2], sc[n][3]);
      int chunk = (n * 2 + (lg >> 1)) ^ (lm & 7);
      *(uint2*)((char*)&Ps[w][0] + lm * 128 + chunk * 16 + (lg & 1) * 8) = val;
    }
    // rescale O by per-q factor (cc lives in lane lm=q; O rows are q=lg*4+j)
    float ccq[4];
    for (int j = 0; j < 4; ++j) ccq[j] = __shfl(cc, lg * 4 + j, 16);
    for (int dt = 0; dt < 4; ++dt)
      for (int j = 0; j < 4; ++j) o[dt][j] *= ccq[j];

    // wave-local: all lanes' P writes visible before fragment reads
    asm volatile("s_waitcnt lgkmcnt(0)" ::: "memory");
    __builtin_amdgcn_sched_barrier(0);

    short8 pf[2];
    for (int kc = 0; kc < 2; ++kc)
      pf[kc] = *(const short8*)((char*)&Ps[w][0] + lm * 128 +
                                (((kc * 4 + lg) ^ (lm & 7)) * 16));
    for (int dt = 0; dt < 4; ++dt)
      for (int kc = 0; kc < 2; ++kc) {
        short8 vf = *(const short8*)(&Vt[cur][(dt * 16 + lm) * 64 +
                                              ((kc * 4 + lg) ^ (lm & 7)) * 8]);
        o[dt] = __builtin_amdgcn_mfma_f32_16x16x32_bf16(pf[kc], vf, o[dt], 0, 0, 0);
      }
    __syncthreads();  // drains vmcnt(0): next tile resident; LDS reads done
  }

  // epilogue: normalize (lrun lives in lane lm=q; O rows are q=lg*4+j)
  float lr[4];
  for (int j = 0; j < 4; ++j) lr[j] = __shfl(lrun, lg * 4 + j, 16);
  for (int dt = 0; dt < 4; ++dt)
    for (int j = 0; j < 4; ++j)
      Ob[baseQ + (long)(q0w + lg * 4 + j) * Dm + dt * 16 + lm] =
          f2bf(o[dt][j] / lr[j]);
}

extern "C" void kernel_launch(void* const* d_in, const int* in_sizes, int n_in,
                              void* d_out, int out_size, void* d_ws, size_t ws_size,
                              hipStream_t stream) {
  const float* query = (const float*)d_in[0];
  const float* key_  = (const float*)d_in[1];
  const float* value = (const float*)d_in[2];
  const float* Wq = (const float*)d_in[3]; const float* bq = (const float*)d_in[4];
  const float* Wk = (const float*)d_in[5]; const float* bk = (const float*)d_in[6];
  const float* Wv = (const float*)d_in[7]; const float* bv = (const float*)d_in[8];
  const float* Wo = (const float*)d_in[9]; const float* bo = (const float*)d_in[10];

  const long NT = (long)2 * Sm * Dm;  // elements per [B,S,D] tensor
  short* Xq = (short*)d_ws;
  short* Xk = Xq + NT;
  short* Xv = Xk + NT;
  short* Wt = Xv + NT;                 // [4][512][512] bf16
  short* Qb = Wt + 4 * 512 * 512;
  short* Kb = Qb + NT;
  short* Vb = Kb + NT;
  short* VT = Xv;                      // reuse Xv (dead after V projection)
  short* Ob = Xq;                      // reuse Xq (dead after Q projection)

  cast_qkv<<<dim3(4096, 3), 256, 0, stream>>>(query, key_, value, Xq, Xk, Xv);
  wtrans<<<dim3(4096), 256, 0, stream>>>(Wq, Wk, Wv, Wo, Wt);

  gemm_bt<true><<<dim3(4, 64), 256, 0, stream>>>(Xq, Wt,               bq, QSCALE, Qb);
  gemm_bt<true><<<dim3(4, 64), 256, 0, stream>>>(Xk, Wt + 512 * 512,   bk, 1.f, Kb);
  gemm_bt<true><<<dim3(4, 64), 256, 0, stream>>>(Xv, Wt + 2 * 512 * 512, bv, 1.f, Vb);

  vtrans<<<dim3(Sm / 64, Dm / 64, 2), 256, 0, stream>>>(Vb, VT);

  attn<<<dim3(Sm / 64, 2 * Hh), 256, 0, stream>>>(Qb, Kb, VT, Ob);

  gemm_bt<false><<<dim3(4, 64), 256, 0, stream>>>(Ob, Wt + 3 * 512 * 512, bo, 1.f, d_out);
}

// Round 4
// 200.928 us; speedup vs baseline: 2.4182x; 1.0550x over previous
//
#include <hip/hip_runtime.h>

typedef short short8 __attribute__((ext_vector_type(8)));
typedef short short4v __attribute__((ext_vector_type(4)));
typedef float f32x4 __attribute__((ext_vector_type(4)));

typedef __attribute__((address_space(1))) void gvoid;
typedef __attribute__((address_space(3))) void lvoid;

#define DEV static __device__ __forceinline__

constexpr int Dm = 512;   // model dim
constexpr int Sm = 4096;  // seq len
constexpr int Hh = 8;     // heads

// 0.125 (=1/sqrt(64)) * log2(e): folded into Q projection so softmax runs in exp2 domain
#define QSCALE 0.18033688011112042f

DEV short f2bf(float f) {
  union { float f; unsigned u; } v; v.f = f;
  unsigned r = v.u + 0x7FFFu + ((v.u >> 16) & 1u);
  return (short)(r >> 16);
}

DEV float exp2_fast(float x) {
#if __has_builtin(__builtin_amdgcn_exp2f)
  return __builtin_amdgcn_exp2f(x);
#else
  return exp2f(x);
#endif
}

DEV float max3f(float a, float b, float c) { return fmaxf(fmaxf(a, b), c); }

DEV unsigned cvt_pk_bf16(float lo, float hi) {
  unsigned r;
  asm("v_cvt_pk_bf16_f32 %0, %1, %2" : "=v"(r) : "v"(lo), "v"(hi));
  return r;
}

DEV void async16(const void* g, void* l) {
  __builtin_amdgcn_global_load_lds((gvoid*)g, (lvoid*)l, 16, 0, 0);
}

// ---------------- input casts ----------------
__global__ __launch_bounds__(256) void cast_qkv(
    const float* __restrict__ q, const float* __restrict__ k,
    const float* __restrict__ v, short* __restrict__ xq,
    short* __restrict__ xk, short* __restrict__ xv) {
  int t = blockIdx.y;
  const float* src = (t == 0) ? q : (t == 1) ? k : v;
  short* dst = (t == 0) ? xq : (t == 1) ? xk : xv;
  long i = (long)(blockIdx.x * 256 + threadIdx.x) * 4;
  float4 f = *(const float4*)(src + i);
  short4v o;
  o[0] = f2bf(f.x); o[1] = f2bf(f.y); o[2] = f2bf(f.z); o[3] = f2bf(f.w);
  *(short4v*)(dst + i) = o;
}

// Wt[w][n][k] = W_w[k][n]  (bf16) — tiled LDS transpose, coalesced both sides
__global__ __launch_bounds__(256) void wtrans(
    const float* __restrict__ wq, const float* __restrict__ wk,
    const float* __restrict__ wv, const float* __restrict__ wo,
    short* __restrict__ wt) {
  __shared__ short T[64 * 72];
  const int tid = threadIdx.x;
  const int n0 = blockIdx.x * 64, k0 = blockIdx.y * 64, w = blockIdx.z;
  const float* W = (w == 0) ? wq : (w == 1) ? wk : (w == 2) ? wv : wo;
  for (int t = 0; t < 4; ++t) {
    int flat = t * 256 + tid;            // 1024 float4 = 64 rows x 16
    int r = flat >> 4, c4 = flat & 15;
    float4 f = *(const float4*)(W + (k0 + r) * 512 + n0 + c4 * 4);
    T[(c4 * 4 + 0) * 72 + r] = f2bf(f.x);
    T[(c4 * 4 + 1) * 72 + r] = f2bf(f.y);
    T[(c4 * 4 + 2) * 72 + r] = f2bf(f.z);
    T[(c4 * 4 + 3) * 72 + r] = f2bf(f.w);
  }
  __syncthreads();
  for (int t = 0; t < 2; ++t) {
    int flat = t * 256 + tid;            // 512 short8 = 64 rows x 8
    int r = flat >> 3, c = flat & 7;
    short8 v = *(const short8*)(T + r * 72 + c * 8);
    *(short8*)(wt + ((long)w << 18) + (n0 + r) * 512 + k0 + c * 8) = v;
  }
}

// ---------------- V transpose: V[b*S+s][d] -> VT[b][d][s] ----------------
__global__ __launch_bounds__(256) void vtrans(
    const short* __restrict__ V, short* __restrict__ VT) {
  __shared__ short T[64 * 72];
  const int tid = threadIdx.x;
  const int s0 = blockIdx.x * 64, d0 = blockIdx.y * 64, b = blockIdx.z;
  for (int t = 0; t < 2; ++t) {
    int flat = t * 256 + tid;
    int sl = flat >> 3, c = flat & 7;
    short8 v = *(const short8*)(V + ((long)b * Sm + s0 + sl) * Dm + d0 + c * 8);
    for (int j = 0; j < 8; ++j) T[(c * 8 + j) * 72 + sl] = v[j];
  }
  __syncthreads();
  for (int t = 0; t < 2; ++t) {
    int flat = t * 256 + tid;
    int dl = flat >> 3, c = flat & 7;
    short8 v = *(const short8*)(T + dl * 72 + c * 8);
    *(short8*)(VT + ((long)b * Dm + d0 + dl) * Sm + s0 + c * 8) = v;
  }
}

// ---------------- GEMM core: Y[m][n] = (sum_k A[m][k]*Bt[n][k] + bias[n])*scale
template <bool OUT_BF16>
DEV void gemm_body(const short* __restrict__ A, const short* __restrict__ Bt,
                   const float* __restrict__ bias, float scale,
                   void* __restrict__ Yv, short* As, short* Bs) {
  constexpr int K = 512, N = 512, BK = 64;
  const int tid = threadIdx.x, lane = tid & 63, w = tid >> 6;
  const int lm = lane & 15, lg = lane >> 4;
  const int wr = w >> 1, wc = w & 1;
  const long bm = (long)blockIdx.y * 128;
  const long bn = (long)blockIdx.x * 128;
  f32x4 zero = {0.f, 0.f, 0.f, 0.f};
  f32x4 acc[4][4];
  for (int m = 0; m < 4; ++m)
    for (int n = 0; n < 4; ++n) acc[m][n] = zero;
  for (int k0 = 0; k0 < K; k0 += BK) {
    __syncthreads();
    for (int t = 0; t < 4; ++t) {
      int flat = t * 256 + tid;
      int row = flat >> 3, c = flat & 7;
      async16(A + (bm + row) * K + k0 + ((c ^ (row & 7)) * 8), As + flat * 8);
    }
    for (int t = 0; t < 4; ++t) {
      int flat = t * 256 + tid;
      int row = flat >> 3, c = flat & 7;
      async16(Bt + (bn + row) * K + k0 + ((c ^ (row & 7)) * 8), Bs + flat * 8);
    }
    __syncthreads();
    for (int kk = 0; kk < 2; ++kk) {
      short8 a[4], b[4];
      for (int m = 0; m < 4; ++m)
        a[m] = *(const short8*)(As + (wr * 64 + m * 16 + lm) * BK +
                                ((kk * 4 + lg) ^ (lm & 7)) * 8);
      for (int n = 0; n < 4; ++n)
        b[n] = *(const short8*)(Bs + (wc * 64 + n * 16 + lm) * BK +
                                ((kk * 4 + lg) ^ (lm & 7)) * 8);
      for (int m = 0; m < 4; ++m)
        for (int n = 0; n < 4; ++n)
          acc[m][n] = __builtin_amdgcn_mfma_f32_16x16x32_bf16(a[m], b[n], acc[m][n], 0, 0, 0);
    }
  }
  for (int m = 0; m < 4; ++m)
    for (int n = 0; n < 4; ++n) {
      long row0 = bm + wr * 64 + m * 16 + lg * 4;
      int col = (int)bn + wc * 64 + n * 16 + lm;
      float bb = bias[col];
      for (int j = 0; j < 4; ++j) {
        float val = (acc[m][n][j] + bb) * scale;
        if (OUT_BF16)
          ((short*)Yv)[(row0 + j) * N + col] = f2bf(val);
        else
          ((float*)Yv)[(row0 + j) * N + col] = val;
      }
    }
}

// fused Q/K/V projections (blockIdx.z selects)
__global__ __launch_bounds__(256) void gemm_proj(
    const short* __restrict__ Xq, const short* __restrict__ Xk,
    const short* __restrict__ Xv, const short* __restrict__ Wt,
    const float* __restrict__ bq, const float* __restrict__ bk,
    const float* __restrict__ bv, short* __restrict__ Qb,
    short* __restrict__ Kb, short* __restrict__ Vb) {
  __shared__ short As[128 * 64];
  __shared__ short Bs[128 * 64];
  int z = blockIdx.z;
  const short* A = (z == 0) ? Xq : (z == 1) ? Xk : Xv;
  const short* Bt = Wt + (long)z * 512 * 512;
  const float* bias = (z == 0) ? bq : (z == 1) ? bk : bv;
  short* Y = (z == 0) ? Qb : (z == 1) ? Kb : Vb;
  float scale = (z == 0) ? QSCALE : 1.f;
  gemm_body<true>(A, Bt, bias, scale, Y, As, Bs);
}

__global__ __launch_bounds__(256) void gemm_out(
    const short* __restrict__ A, const short* __restrict__ Bt,
    const float* __restrict__ bias, float* __restrict__ Y) {
  __shared__ short As[128 * 64];
  __shared__ short Bs[128 * 64];
  gemm_body<false>(A, Bt, bias, 1.f, Y, As, Bs);
}

// ---------------- flash attention: 4 waves x 32 q-rows, swapped QK^T -------
// Round-2-exact softmax semantics (always rescale, VALU lnew); widened to qt=2.
__global__ __launch_bounds__(256) void attn(
    const short* __restrict__ Qb, const short* __restrict__ Kb,
    const short* __restrict__ VTb, short* __restrict__ Ob) {
  __shared__ short Ks[2][64 * 64];  // [kv][d], 16B-chunk c at c^(kv&7)
  __shared__ short Vt[2][64 * 64];  // [d][kv], chunk c at c^(d&7)
  __shared__ short Ps[4][32 * 64];  // per-wave [q][kv], swizzled
  const int tid = threadIdx.x, lane = tid & 63, w = tid >> 6;
  const int lm = lane & 15, lg = lane >> 4;
  const int bh = blockIdx.y, b = bh >> 3, h = bh & 7;
  const long baseQ = (long)b * Sm * Dm + h * 64;
  const long baseVT = ((long)b * Dm + h * 64) * Sm;
  const int q0w = blockIdx.x * 128 + w * 32;

  // Q fragments (B-operand): lane lm = q, regs = d; qt picks 16-row half
  short8 qf[2][2];
  for (int qt = 0; qt < 2; ++qt)
    for (int c = 0; c < 2; ++c)
      qf[qt][c] = *(const short8*)(Qb + baseQ + (long)(q0w + qt * 16 + lm) * Dm +
                                   c * 32 + lg * 8);

  f32x4 o[2][4];
  for (int qt = 0; qt < 2; ++qt)
    for (int dt = 0; dt < 4; ++dt) o[qt][dt] = {0.f, 0.f, 0.f, 0.f};
  float mrun[2] = {-1e30f, -1e30f};
  float lrun[2] = {0.f, 0.f};

  // hoisted per-thread staging pointers (advance by constant stride per tile)
  const int r0 = tid >> 3, c0 = tid & 7;          // chunks 0..255
  const int r1 = 32 + (tid >> 3);                 // chunks 256..511
  const short* gk0 = Kb + baseQ + (long)r0 * Dm + (c0 ^ (r0 & 7)) * 8;
  const short* gk1 = Kb + baseQ + (long)r1 * Dm + (c0 ^ (r1 & 7)) * 8;
  const short* gv0 = VTb + baseVT + (long)r0 * Sm + (c0 ^ (r0 & 7)) * 8;
  const short* gv1 = VTb + baseVT + (long)r1 * Sm + (c0 ^ (r1 & 7)) * 8;
  const int l0 = tid * 8, l1 = (256 + tid) * 8;

  // prologue: stage tile 0
  async16(gk0, &Ks[0][l0]); async16(gk1, &Ks[0][l1]);
  async16(gv0, &Vt[0][l0]); async16(gv1, &Vt[0][l1]);
  gk0 += 64 * Dm; gk1 += 64 * Dm; gv0 += 64; gv1 += 64;
  __syncthreads();

  constexpr int NTILES = Sm / 64;
  for (int it = 0; it < NTILES; ++it) {
    const int cur = it & 1;
    if (it + 1 < NTILES) {  // prefetch next tile (drained by end-of-loop barrier)
      async16(gk0, &Ks[cur ^ 1][l0]); async16(gk1, &Ks[cur ^ 1][l1]);
      async16(gv0, &Vt[cur ^ 1][l0]); async16(gv1, &Vt[cur ^ 1][l1]);
      gk0 += 64 * Dm; gk1 += 64 * Dm; gv0 += 64; gv1 += 64;
    }

    // QK^T swapped: lane holds sc[qt][n][j] = S[kv=n*16+lg*4+j][q=qt*16+lm]
    f32x4 sc[2][4];
    for (int n = 0; n < 4; ++n) {
      sc[0][n] = {0.f, 0.f, 0.f, 0.f};
      sc[1][n] = {0.f, 0.f, 0.f, 0.f};
      for (int kk = 0; kk < 2; ++kk) {
        short8 kf = *(const short8*)(&Ks[cur][(n * 16 + lm) * 64 +
                                              ((kk * 4 + lg) ^ (lm & 7)) * 8]);
        sc[0][n] = __builtin_amdgcn_mfma_f32_16x16x32_bf16(kf, qf[0][kk], sc[0][n], 0, 0, 0);
        sc[1][n] = __builtin_amdgcn_mfma_f32_16x16x32_bf16(kf, qf[1][kk], sc[1][n], 0, 0, 0);
      }
    }
    // per-row max (exp2 domain), always-rescale online softmax (round-2 exact)
    float mi[2], cc[2];
    for (int qt = 0; qt < 2; ++qt) {
      float t0 = max3f(sc[qt][0][0], sc[qt][0][1], sc[qt][0][2]);
      float t1 = max3f(sc[qt][0][3], sc[qt][1][0], sc[qt][1][1]);
      float t2 = max3f(sc[qt][1][2], sc[qt][1][3], sc[qt][2][0]);
      float t3 = max3f(sc[qt][2][1], sc[qt][2][2], sc[qt][2][3]);
      float t4 = max3f(sc[qt][3][0], sc[qt][3][1], sc[qt][3][2]);
      float r = max3f(t0, t1, t2);
      float s = max3f(t3, t4, sc[qt][3][3]);
      float tm = fmaxf(r, s);
      tm = fmaxf(tm, __shfl_xor(tm, 16, 64));
      tm = fmaxf(tm, __shfl_xor(tm, 32, 64));
      mi[qt] = fmaxf(mrun[qt], tm);
      cc[qt] = exp2_fast(mrun[qt] - mi[qt]);
      mrun[qt] = mi[qt];
    }
    // P = exp2(sc - mi), accumulate row-sum in VALU, pack to per-wave LDS
    float lnew[2] = {0.f, 0.f};
    for (int qt = 0; qt < 2; ++qt)
      for (int n = 0; n < 4; ++n) {
        float p0 = exp2_fast(sc[qt][n][0] - mi[qt]);
        float p1 = exp2_fast(sc[qt][n][1] - mi[qt]);
        float p2 = exp2_fast(sc[qt][n][2] - mi[qt]);
        float p3 = exp2_fast(sc[qt][n][3] - mi[qt]);
        lnew[qt] += (p0 + p1) + (p2 + p3);
        uint2 val;
        val.x = cvt_pk_bf16(p0, p1);
        val.y = cvt_pk_bf16(p2, p3);
        int chunk = (n * 2 + (lg >> 1)) ^ (lm & 7);
        *(uint2*)((char*)&Ps[w][0] + (qt * 16 + lm) * 128 + chunk * 16 +
                  (lg & 1) * 8) = val;
      }
    for (int qt = 0; qt < 2; ++qt) {
      lnew[qt] += __shfl_xor(lnew[qt], 16, 64);
      lnew[qt] += __shfl_xor(lnew[qt], 32, 64);
      lrun[qt] = lrun[qt] * cc[qt] + lnew[qt];
      // rescale O by per-q factor (cc lives in lane lm=q; O rows are lg*4+j)
      float ccq[4];
      for (int j = 0; j < 4; ++j) ccq[j] = __shfl(cc[qt], lg * 4 + j, 16);
      for (int dt = 0; dt < 4; ++dt)
        for (int j = 0; j < 4; ++j) o[qt][dt][j] *= ccq[j];
    }
    // wave-local: all lanes' P writes visible before fragment reads
    asm volatile("s_waitcnt lgkmcnt(0)" ::: "memory");
    __builtin_amdgcn_sched_barrier(0);

    short8 pf[2][2];
    for (int qt = 0; qt < 2; ++qt)
      for (int kc = 0; kc < 2; ++kc)
        pf[qt][kc] = *(const short8*)((char*)&Ps[w][0] + (qt * 16 + lm) * 128 +
                                      (((kc * 4 + lg) ^ (lm & 7)) * 16));
    // PV: O[q][d] += sum_kv P[q][kv] * V[kv][d]
    for (int dt = 0; dt < 4; ++dt)
      for (int kc = 0; kc < 2; ++kc) {
        short8 vf = *(const short8*)(&Vt[cur][(dt * 16 + lm) * 64 +
                                              ((kc * 4 + lg) ^ (lm & 7)) * 8]);
        o[0][dt] = __builtin_amdgcn_mfma_f32_16x16x32_bf16(pf[0][kc], vf, o[0][dt], 0, 0, 0);
        o[1][dt] = __builtin_amdgcn_mfma_f32_16x16x32_bf16(pf[1][kc], vf, o[1][dt], 0, 0, 0);
      }
    __syncthreads();  // next tile resident (vmcnt drained); LDS reads done
  }

  // epilogue: normalize (lrun lives in lane lm=q; O rows are q=lg*4+j)
  for (int qt = 0; qt < 2; ++qt) {
    float lr[4];
    for (int j = 0; j < 4; ++j) lr[j] = __shfl(lrun[qt], lg * 4 + j, 16);
    for (int dt = 0; dt < 4; ++dt)
      for (int j = 0; j < 4; ++j)
        Ob[baseQ + (long)(q0w + qt * 16 + lg * 4 + j) * Dm + dt * 16 + lm] =
            f2bf(o[qt][dt][j] / lr[j]);
  }
}

extern "C" void kernel_launch(void* const* d_in, const int* in_sizes, int n_in,
                              void* d_out, int out_size, void* d_ws, size_t ws_size,
                              hipStream_t stream) {
  const float* query = (const float*)d_in[0];
  const float* key_  = (const float*)d_in[1];
  const float* value = (const float*)d_in[2];
  const float* Wq = (const float*)d_in[3]; const float* bq = (const float*)d_in[4];
  const float* Wk = (const float*)d_in[5]; const float* bk = (const float*)d_in[6];
  const float* Wv = (const float*)d_in[7]; const float* bv = (const float*)d_in[8];
  const float* Wo = (const float*)d_in[9]; const float* bo = (const float*)d_in[10];

  const long NT = (long)2 * Sm * Dm;  // elements per [B,S,D] tensor
  short* Xq = (short*)d_ws;
  short* Xk = Xq + NT;
  short* Xv = Xk + NT;
  short* Wt = Xv + NT;                 // [4][512][512] bf16
  short* Qb = Wt + 4 * 512 * 512;
  short* Kb = Qb + NT;
  short* Vb = Kb + NT;
  short* VT = Xv;                      // reuse Xv (dead after V projection)
  short* Ob = Xq;                      // reuse Xq (dead after Q projection)

  cast_qkv<<<dim3(4096, 3), 256, 0, stream>>>(query, key_, value, Xq, Xk, Xv);
  wtrans<<<dim3(8, 8, 4), 256, 0, stream>>>(Wq, Wk, Wv, Wo, Wt);

  gemm_proj<<<dim3(4, 64, 3), 256, 0, stream>>>(Xq, Xk, Xv, Wt, bq, bk, bv,
                                                Qb, Kb, Vb);

  vtrans<<<dim3(Sm / 64, Dm / 64, 2), 256, 0, stream>>>(Vb, VT);

  attn<<<dim3(Sm / 128, 2 * Hh), 256, 0, stream>>>(Qb, Kb, VT, Ob);

  gemm_out<<<dim3(4, 64), 256, 0, stream>>>(Ob, Wt + 3L * 512 * 512, bo,
                                            (float*)d_out);
}